// Round 2
// baseline (2672.302 us; speedup 1.0000x reference)
//
#include <hip/hip_runtime.h>
#include <cstdint>

#define N 8192
#define NT 128      // 64-col chunks per row (N/64)
typedef unsigned long long u64;
typedef unsigned int u32;

// ---------------------------------------------------------------------------
// K1: rank by counting, keys recomputed inline from scores (descending score,
// stable ascending index). Partial counts per y-slab -> rankpart[8][N]; no
// atomics, no zero-init kernel needed.
// ---------------------------------------------------------------------------
__global__ __launch_bounds__(256) void k_rank(const float* __restrict__ scores,
                                              int* __restrict__ rankpart) {
  __shared__ u64 tile[1024];
  int e = blockIdx.x * 256 + threadIdx.x;
  int j0 = blockIdx.y * 1024;
  for (int t = threadIdx.x; t < 1024; t += 256) {
    int j = j0 + t;
    tile[t] = ((u64)__float_as_uint(scores[j]) << 32) | (unsigned)(0xFFFFFFFFu - (unsigned)j);
  }
  __syncthreads();
  u64 ke = ((u64)__float_as_uint(scores[e]) << 32) | (unsigned)(0xFFFFFFFFu - (unsigned)e);
  int c = 0;
#pragma unroll 8
  for (int k = 0; k < 1024; ++k) c += (tile[k] > ke) ? 1 : 0;
  rankpart[blockIdx.y * N + e] = c;
}

// ---------------------------------------------------------------------------
// K2: sum rank partials + scatter into sorted SoA (clipped coords, score,
// area) + init aux (cnt, prob, packed-first). D is fully written by k_sweep.
// ---------------------------------------------------------------------------
__global__ __launch_bounds__(256) void k_scatter(const float* __restrict__ boxes,
                                                 const float* __restrict__ scores,
                                                 const int* __restrict__ rankpart,
                                                 float* __restrict__ bx1s, float* __restrict__ by1s,
                                                 float* __restrict__ bx2s, float* __restrict__ by2s,
                                                 float* __restrict__ ss, float* __restrict__ areas,
                                                 int* __restrict__ cnt,
                                                 float* __restrict__ prob,
                                                 u64* __restrict__ pk) {
#pragma clang fp contract(off)
  int i = blockIdx.x * 256 + threadIdx.x;
  if (i >= N) return;
  int r = 0;
#pragma unroll
  for (int q = 0; q < 8; ++q) r += rankpart[q * N + i];
  float x1 = fminf(fmaxf(boxes[i * 4 + 0], 0.0f), 1920.0f);
  float y1 = fminf(fmaxf(boxes[i * 4 + 1], 0.0f), 1080.0f);
  float x2 = fminf(fmaxf(boxes[i * 4 + 2], 0.0f), 1920.0f);
  float y2 = fminf(fmaxf(boxes[i * 4 + 3], 0.0f), 1080.0f);
  bx1s[r] = x1; by1s[r] = y1; bx2s[r] = x2; by2s[r] = y2;
  ss[r] = scores[i];
  areas[r] = (x2 - x1 + 1.0f) * (y2 - y1 + 1.0f);
  cnt[i] = 0;
  prob[i] = 0.0f;
  pk[i] = 0ull;
}

// ---------------------------------------------------------------------------
// K3: adjacency, SYMMETRIC lower-triangle blocks + ballot transpose.
// Band trick (verified absmax 0.0): iou>0.5 <=> 2*inter>uni whenever
// |2*inter-uni| > 1e-6*uni (RN div error <= 3e-8 rel << band margin); only
// in-band lanes take the exact IEEE divide, ballot-guarded.
// fp contract OFF everywhere; matrix float-exact symmetric.
// ---------------------------------------------------------------------------
__global__ __launch_bounds__(64) void k_adj(const float* __restrict__ bx1s, const float* __restrict__ by1s,
                                            const float* __restrict__ bx2s, const float* __restrict__ by2s,
                                            const float* __restrict__ areas,
                                            u64* __restrict__ mtile,
                                            u64* __restrict__ mrow) {
#pragma clang fp contract(off)
  __shared__ float jx1[64], jy1[64], jx2[64], jy2[64], ja[64];
  int p = blockIdx.x;
  int gy = (int)((sqrtf(8.0f * (float)p + 1.0f) - 1.0f) * 0.5f);
  while ((gy + 1) * (gy + 2) / 2 <= p) ++gy;
  while (gy * (gy + 1) / 2 > p) --gy;
  int gx = p - gy * (gy + 1) / 2;

  int l = threadIdx.x;
  int j = gx * 64 + l;
  jx1[l] = bx1s[j]; jy1[l] = by1s[j]; jx2[l] = bx2s[j]; jy2[l] = by2s[j]; ja[l] = areas[j];
  __syncthreads();
  int i = gy * 64 + l;
  float x1 = bx1s[i], y1 = by1s[i], x2 = bx2s[i], y2 = by2s[i], ai = areas[i];
  u64 bits = 0;
#pragma unroll 4
  for (int jj = 0; jj < 64; ++jj) {
    float ix1 = fmaxf(x1, jx1[jj]);
    float iy1 = fmaxf(y1, jy1[jj]);
    float ix2 = fminf(x2, jx2[jj]);
    float iy2 = fminf(y2, jy2[jj]);
    float iw = fmaxf(ix2 - ix1 + 1.0f, 0.0f);
    float ih = fmaxf(iy2 - iy1 + 1.0f, 0.0f);
    float inter = iw * ih;
    float uni = (ai + ja[jj]) - inter;   // uni > 0 always (areas >= 1)
    float t = inter + inter;             // exact (x2)
    bool gt = t > uni;
    bool amb = fabsf(t - uni) <= 1e-6f * uni;
    if (__ballot(amb) != 0ull) {         // ~never taken
      float iou = inter / uni;           // exact IEEE div, matches numpy
      if (amb) gt = iou > 0.5f;
    }
    bits |= ((u64)gt) << jj;
  }
  mtile[((size_t)gy * NT + gx) * 64 + l] = bits;
  mrow[(size_t)i * NT + gx] = bits;
  if (gx != gy) {
    u64 tb = 0;
#pragma unroll 8
    for (int c = 0; c < 64; ++c) {
      u64 wb = __ballot((bits >> c) & 1ull);
      tb = (l == c) ? wb : tb;
    }
    mtile[((size_t)gx * NT + gy) * 64 + l] = tb;
    mrow[(size_t)(gx * 64 + l) * NT + gy] = tb;
  }
}

// ---------------------------------------------------------------------------
// K4: EXACT single-sweep greedy classification, ONE wave, dual (suppressed-
// bitmap) form. Replaces rounds + ballot-fix entirely.
//
// Invariants (greedy MIS): heads are pairwise non-adjacent; every non-head is
// adjacent to an earlier head. Hence, processing j ascending with
// R = OR of rows of heads processed so far:
//   bit j of R clear  <=>  j is a head      (exact, by induction)
// Per non-head: ONE bit test (readlane+shift), no row load, no ballot.
// Per head: OR its coalesced 1KB row (ulong2/lane) into R.
// Candidates (elements unsuppressed at scan time ~= heads + small window) are
// generated by a scan pointer running ~32 candidates ahead, which skips
// already-suppressed elements word-wise for free; their rows are prefetched
// via two 16-deep statically-unrolled batches (registers, no scratch).
// Scan-time filtering is sound: R only grows, so scan-time-set => suppressed.
// Process-time re-test catches in-window suppressions.
// ---------------------------------------------------------------------------
__global__ __launch_bounds__(64, 1) void k_sweep(const u64* __restrict__ mrow,
                                                 u64* __restrict__ D) {
  int l = threadIdx.x;
  u64 R0 = 0, R1 = 0;      // lane l holds suppressed-words 2l, 2l+1
  u64 D0 = 0, D1 = 0;      // lane l holds head-words 2l, 2l+1

  int sw = 0;              // next scan word
  int swb = 0;             // word index for current scan mask
  u64 sm = 0;              // remaining candidate bits in word swb

  auto getR = [&](int w) -> u64 {
    u64 x = (w & 1) ? R1 : R0;                       // w uniform
    unsigned lo = __builtin_amdgcn_readlane((unsigned)(x & 0xFFFFFFFFull), w >> 1);
    unsigned hi = __builtin_amdgcn_readlane((unsigned)(x >> 32), w >> 1);
    return ((u64)hi << 32) | (u64)lo;
  };
  auto next_cand = [&]() -> int {
    while (sm == 0) {
      if (sw >= NT) return -1;
      swb = sw;
      sm = ~getR(sw);      // unsuppressed-at-scan-time = candidates (superset of heads)
      ++sw;
    }
    int b = __builtin_ctzll(sm);
    sm &= sm - 1;
    return swb * 64 + b;
  };

  int jA[16], jB[16];
  ulong2 rA[16], rB[16];

#pragma unroll
  for (int q = 0; q < 16; ++q) {
    int j = next_cand();
    jA[q] = j;
    int jj = (j >= 0) ? j : 0;
    rA[q] = *(const ulong2*)&mrow[(size_t)jj * NT + 2 * l];
  }
#pragma unroll
  for (int q = 0; q < 16; ++q) {
    int j = next_cand();
    jB[q] = j;
    int jj = (j >= 0) ? j : 0;
    rB[q] = *(const ulong2*)&mrow[(size_t)jj * NT + 2 * l];
  }

  while (true) {
    if (jA[0] < 0) break;
#pragma unroll
    for (int q = 0; q < 16; ++q) {
      int j = jA[q];
      if (j < 0) break;                        // uniform
      u64 wj = getR(j >> 6);
      bool head = !((wj >> (j & 63)) & 1ull);  // uniform
      u64 hm = head ? ~0ull : 0ull;
      R0 |= rA[q].x & hm;
      R1 |= rA[q].y & hm;
      u64 bset = 1ull << (j & 63);
      bool own = ((j >> 7) == l);
      bool hi = ((j >> 6) & 1);
      D0 |= (head && own && !hi) ? bset : 0ull;
      D1 |= (head && own && hi) ? bset : 0ull;
    }
#pragma unroll
    for (int q = 0; q < 16; ++q) {             // refill A (candidates 2 batches ahead)
      int j = next_cand();
      jA[q] = j;
      int jj = (j >= 0) ? j : 0;
      rA[q] = *(const ulong2*)&mrow[(size_t)jj * NT + 2 * l];
    }
    if (jB[0] < 0) break;
#pragma unroll
    for (int q = 0; q < 16; ++q) {
      int j = jB[q];
      if (j < 0) break;
      u64 wj = getR(j >> 6);
      bool head = !((wj >> (j & 63)) & 1ull);
      u64 hm = head ? ~0ull : 0ull;
      R0 |= rB[q].x & hm;
      R1 |= rB[q].y & hm;
      u64 bset = 1ull << (j & 63);
      bool own = ((j >> 7) == l);
      bool hi = ((j >> 6) & 1);
      D0 |= (head && own && !hi) ? bset : 0ull;
      D1 |= (head && own && hi) ? bset : 0ull;
    }
#pragma unroll
    for (int q = 0; q < 16; ++q) {             // refill B
      int j = next_cand();
      jB[q] = j;
      int jj = (j >= 0) ? j : 0;
      rB[q] = *(const ulong2*)&mrow[(size_t)jj * NT + 2 * l];
    }
  }

  D[2 * l] = D0;
  D[2 * l + 1] = D1;
}

// ---------------------------------------------------------------------------
// K5: parallel cluster assignment + segment atomics. cluster[j] = first head
// adjacent to j; that head index is provably <= j (j self-adjacent if head,
// else suppressed by an earlier adjacent head) -> scan only tiles k <= gy.
// Fused "first index at cluster-max y2" via ONE packed u64 atomicMax:
// (y2_bits << 32) | ~j  -- y2 >= 0 so uint order == float order; tie -> min j,
// exactly the reference's segment_min over cand = (y2 >= segmax).
// ---------------------------------------------------------------------------
__global__ __launch_bounds__(256) void k_cluster(const u64* __restrict__ mtile,
                                                 const u64* __restrict__ D,
                                                 const float* __restrict__ ss,
                                                 const float* __restrict__ by2s,
                                                 int* __restrict__ cluster,
                                                 int* __restrict__ cnt,
                                                 float* __restrict__ prob,
                                                 u64* __restrict__ pk) {
  __shared__ u64 hlds[NT];
  __shared__ int red[4][64];
  int gy = blockIdx.x;
  if (threadIdx.x < NT) hlds[threadIdx.x] = D[threadIdx.x];
  __syncthreads();
  int w = threadIdx.x >> 6, r = threadIdx.x & 63;
  int best = 0x7fffffff;
  for (int k = w; k <= gy; k += 4) {      // per-group candidates ascend with k
    u64 v = mtile[((size_t)gy * NT + k) * 64 + r] & hlds[k];
    if (v) { best = k * 64 + __builtin_ctzll(v); break; }
  }
  red[w][r] = best;
  __syncthreads();
  if (w == 0) {
    int b = min(min(red[0][r], red[1][r]), min(red[2][r], red[3][r]));
    int j = gy * 64 + r;
    cluster[j] = b;
    atomicAdd(&cnt[b], 1);
    atomicAdd(&prob[b], ss[j]);
    atomicMax((unsigned long long*)&pk[b],
              ((u64)__float_as_uint(by2s[j]) << 32) | (u64)(0xFFFFFFFFu - (unsigned)j));
  }
}

// ---------------------------------------------------------------------------
// K6: outputs. out[j][0..4] then keep[j] appended (floats 0/1).
// first index recovered from packed atomicMax: ~low32(pk).
// ---------------------------------------------------------------------------
__global__ __launch_bounds__(256) void k_out(const int* __restrict__ cluster,
                                             const float* __restrict__ bx1s, const float* __restrict__ by1s,
                                             const float* __restrict__ bx2s, const float* __restrict__ by2s,
                                             const int* __restrict__ cnt,
                                             const float* __restrict__ prob,
                                             const u64* __restrict__ pk,
                                             const int* __restrict__ num_models,
                                             float* __restrict__ out) {
  int j = blockIdx.x * 256 + threadIdx.x;
  if (j >= N) return;
  int c = cluster[j];
  int nm = num_models[0];
  bool valid = (float)cnt[c] >= (float)nm / 3.0f;
  unsigned fj = 0xFFFFFFFFu - (unsigned)(pk[c] & 0xFFFFFFFFull);
  bool keep = (fj == (unsigned)j) && valid;
  float o0 = 0.f, o1 = 0.f, o2 = 0.f, o3 = 0.f, o4 = 0.f;
  if (keep) {
    o0 = bx1s[j]; o1 = by1s[j]; o2 = bx2s[j]; o3 = by2s[j];
    o4 = prob[c] / (float)nm;
  }
  out[j * 5 + 0] = o0;
  out[j * 5 + 1] = o1;
  out[j * 5 + 2] = o2;
  out[j * 5 + 3] = o3;
  out[j * 5 + 4] = o4;
  out[N * 5 + j] = keep ? 1.0f : 0.0f;
}

// ---------------------------------------------------------------------------
extern "C" void kernel_launch(void* const* d_in, const int* in_sizes, int n_in,
                              void* d_out, int out_size, void* d_ws, size_t ws_size,
                              hipStream_t stream) {
  const float* boxes = (const float*)d_in[0];
  const float* scores = (const float*)d_in[1];
  const int* num_models = (const int*)d_in[2];
  float* out = (float*)d_out;

  char* p = (char*)d_ws;
  auto take = [&](size_t bytes) {
    char* r = p;
    p += (bytes + 255) & ~(size_t)255;
    return r;
  };
  int* rankpart = (int*)take((size_t)8 * N * 4);
  float* bx1s = (float*)take((size_t)N * 4);
  float* by1s = (float*)take((size_t)N * 4);
  float* bx2s = (float*)take((size_t)N * 4);
  float* by2s = (float*)take((size_t)N * 4);
  float* ss   = (float*)take((size_t)N * 4);
  float* areas= (float*)take((size_t)N * 4);
  int* cluster= (int*)take((size_t)N * 4);
  int* cnt    = (int*)take((size_t)N * 4);
  float* prob = (float*)take((size_t)N * 4);
  u64* pk     = (u64*)take((size_t)N * 8);            // packed (y2max, ~first)
  u64* D      = (u64*)take((size_t)NT * 8);           // head bitmap
  u64* mtile  = (u64*)take((size_t)NT * NT * 64 * 8); // 8 MiB tiled adjacency
  u64* mrow   = (u64*)take((size_t)N * NT * 8);       // 8 MiB row-major adjacency

  k_rank<<<dim3(N / 256, 8), 256, 0, stream>>>(scores, rankpart);
  k_scatter<<<N / 256, 256, 0, stream>>>(boxes, scores, rankpart,
                                         bx1s, by1s, bx2s, by2s, ss, areas,
                                         cnt, prob, pk);
  k_adj<<<NT * (NT + 1) / 2, 64, 0, stream>>>(bx1s, by1s, bx2s, by2s, areas, mtile, mrow);
  k_sweep<<<1, 64, 0, stream>>>(mrow, D);
  k_cluster<<<NT, 256, 0, stream>>>(mtile, D, ss, by2s, cluster, cnt, prob, pk);
  k_out<<<N / 256, 256, 0, stream>>>(cluster, bx1s, by1s, bx2s, by2s, cnt, prob, pk, num_models, out);
}

// Round 3
// 931.772 us; speedup vs baseline: 2.8680x; 2.8680x over previous
//
#include <hip/hip_runtime.h>
#include <cstdint>

#define N 8192
#define NT 128      // 64-col chunks per row (N/64)
typedef unsigned long long u64;
typedef unsigned int u32;

// ---------------------------------------------------------------------------
// K1: rank by counting, keys recomputed inline from scores (descending score,
// stable ascending index). Partial counts per y-slab -> rankpart[8][N].
// ---------------------------------------------------------------------------
__global__ __launch_bounds__(256) void k_rank(const float* __restrict__ scores,
                                              int* __restrict__ rankpart) {
  __shared__ u64 tile[1024];
  int e = blockIdx.x * 256 + threadIdx.x;
  int j0 = blockIdx.y * 1024;
  for (int t = threadIdx.x; t < 1024; t += 256) {
    int j = j0 + t;
    tile[t] = ((u64)__float_as_uint(scores[j]) << 32) | (unsigned)(0xFFFFFFFFu - (unsigned)j);
  }
  __syncthreads();
  u64 ke = ((u64)__float_as_uint(scores[e]) << 32) | (unsigned)(0xFFFFFFFFu - (unsigned)e);
  int c = 0;
#pragma unroll 8
  for (int k = 0; k < 1024; ++k) c += (tile[k] > ke) ? 1 : 0;
  rankpart[blockIdx.y * N + e] = c;
}

// ---------------------------------------------------------------------------
// K2: sum rank partials + scatter into sorted SoA + init aux.
// ---------------------------------------------------------------------------
__global__ __launch_bounds__(256) void k_scatter(const float* __restrict__ boxes,
                                                 const float* __restrict__ scores,
                                                 const int* __restrict__ rankpart,
                                                 float* __restrict__ bx1s, float* __restrict__ by1s,
                                                 float* __restrict__ bx2s, float* __restrict__ by2s,
                                                 float* __restrict__ ss, float* __restrict__ areas,
                                                 int* __restrict__ cnt,
                                                 float* __restrict__ prob,
                                                 u64* __restrict__ pk) {
#pragma clang fp contract(off)
  int i = blockIdx.x * 256 + threadIdx.x;
  if (i >= N) return;
  int r = 0;
#pragma unroll
  for (int q = 0; q < 8; ++q) r += rankpart[q * N + i];
  float x1 = fminf(fmaxf(boxes[i * 4 + 0], 0.0f), 1920.0f);
  float y1 = fminf(fmaxf(boxes[i * 4 + 1], 0.0f), 1080.0f);
  float x2 = fminf(fmaxf(boxes[i * 4 + 2], 0.0f), 1920.0f);
  float y2 = fminf(fmaxf(boxes[i * 4 + 3], 0.0f), 1080.0f);
  bx1s[r] = x1; by1s[r] = y1; bx2s[r] = x2; by2s[r] = y2;
  ss[r] = scores[i];
  areas[r] = (x2 - x1 + 1.0f) * (y2 - y1 + 1.0f);
  cnt[i] = 0;
  prob[i] = 0.0f;
  pk[i] = 0ull;
}

// ---------------------------------------------------------------------------
// K3: adjacency, SYMMETRIC lower-triangle blocks + ballot transpose.
// Band trick (verified absmax 0.0): iou>0.5 <=> 2*inter>uni whenever
// |2*inter-uni| > 1e-6*uni; only in-band lanes take the exact IEEE divide.
// fp contract OFF everywhere; matrix float-exact symmetric.
// ---------------------------------------------------------------------------
__global__ __launch_bounds__(64) void k_adj(const float* __restrict__ bx1s, const float* __restrict__ by1s,
                                            const float* __restrict__ bx2s, const float* __restrict__ by2s,
                                            const float* __restrict__ areas,
                                            u64* __restrict__ mtile,
                                            u64* __restrict__ mrow) {
#pragma clang fp contract(off)
  __shared__ float jx1[64], jy1[64], jx2[64], jy2[64], ja[64];
  int p = blockIdx.x;
  int gy = (int)((sqrtf(8.0f * (float)p + 1.0f) - 1.0f) * 0.5f);
  while ((gy + 1) * (gy + 2) / 2 <= p) ++gy;
  while (gy * (gy + 1) / 2 > p) --gy;
  int gx = p - gy * (gy + 1) / 2;

  int l = threadIdx.x;
  int j = gx * 64 + l;
  jx1[l] = bx1s[j]; jy1[l] = by1s[j]; jx2[l] = bx2s[j]; jy2[l] = by2s[j]; ja[l] = areas[j];
  __syncthreads();
  int i = gy * 64 + l;
  float x1 = bx1s[i], y1 = by1s[i], x2 = bx2s[i], y2 = by2s[i], ai = areas[i];
  u64 bits = 0;
#pragma unroll 4
  for (int jj = 0; jj < 64; ++jj) {
    float ix1 = fmaxf(x1, jx1[jj]);
    float iy1 = fmaxf(y1, jy1[jj]);
    float ix2 = fminf(x2, jx2[jj]);
    float iy2 = fminf(y2, jy2[jj]);
    float iw = fmaxf(ix2 - ix1 + 1.0f, 0.0f);
    float ih = fmaxf(iy2 - iy1 + 1.0f, 0.0f);
    float inter = iw * ih;
    float uni = (ai + ja[jj]) - inter;   // uni > 0 always (areas >= 1)
    float t = inter + inter;             // exact (x2)
    bool gt = t > uni;
    bool amb = fabsf(t - uni) <= 1e-6f * uni;
    if (__ballot(amb) != 0ull) {         // ~never taken
      float iou = inter / uni;           // exact IEEE div, matches numpy
      if (amb) gt = iou > 0.5f;
    }
    bits |= ((u64)gt) << jj;
  }
  mtile[((size_t)gy * NT + gx) * 64 + l] = bits;
  mrow[(size_t)i * NT + gx] = bits;
  if (gx != gy) {
    u64 tb = 0;
#pragma unroll 8
    for (int c = 0; c < 64; ++c) {
      u64 wb = __ballot((bits >> c) & 1ull);
      tb = (l == c) ? wb : tb;
    }
    mtile[((size_t)gx * NT + gy) * 64 + l] = tb;
    mrow[(size_t)(gx * 64 + l) * NT + gy] = tb;
  }
}

// ---------------------------------------------------------------------------
// K4: EXACT single-sweep greedy classification, ONE wave, dual (suppressed-
// bitmap) form. Algorithm identical to round 2 (absmax 0.0); codegen fixed:
// round 2's VGPR_Count=36 proved the prefetch arrays lived in SCRATCH (rule
// #20 -- the unroll pragma failed on loops containing data-dependent whiles,
// leaving runtime indices). Every row then took a ~2300cy scratch round-trip
// (2700 x 2300cy = 2.6ms, matching the measured 2607us).
//
// Now: ZERO arrays. 3 rotating batches x 16 candidates, all state in NAMED
// variables via REP16 macros -> guaranteed register residency. Candidate
// indices are wave-uniform (readlane-based scan) -> SGPRs. A batch's 16
// independent global_load_dwordx4 are issued two segments (~600-800cy) before
// consumption, covering L3 latency. Exhaustion handled by j<0 predication
// (no break inside straight-line regions); only uniform batch-boundary exits.
//
// Invariant (greedy MIS): R = OR of rows of heads processed so far; bit j of
// R clear at j's turn <=> j is a head (exact; candidates are a sound superset
// filtered at scan time, re-tested at process time; production order is
// ascending so all heads < j are in R when j is tested).
// ---------------------------------------------------------------------------
#define REP16(M) M(0) M(1) M(2) M(3) M(4) M(5) M(6) M(7) M(8) M(9) M(10) M(11) M(12) M(13) M(14) M(15)

__global__ __launch_bounds__(64, 1) void k_sweep(const u64* __restrict__ mrow,
                                                 u64* __restrict__ D) {
  int l = threadIdx.x;
  u64 R0 = 0, R1 = 0;      // lane l holds suppressed-words 2l, 2l+1
  u64 D0 = 0, D1 = 0;      // lane l holds head-words 2l, 2l+1
  int sw = 0, swb = 0;     // scan word pointer / current word index
  u64 sm = 0;              // remaining candidate bits in word swb

  auto getR = [&](int w) -> u64 {                    // w uniform
    u64 x = (w & 1) ? R1 : R0;
    unsigned lo = __builtin_amdgcn_readlane((unsigned)x, (w >> 1));
    unsigned hi = __builtin_amdgcn_readlane((unsigned)(x >> 32), (w >> 1));
    return ((u64)hi << 32) | (u64)lo;
  };
  auto next_cand = [&]() -> int {                    // uniform result
    while (sm == 0) {
      if (sw >= NT) return -1;
      swb = sw;
      sm = ~getR(sw);      // unsuppressed-at-scan-time = candidate superset
      ++sw;
    }
    int b = __builtin_ctzll(sm);
    sm &= sm - 1;
    return swb * 64 + b;
  };

#define DECLV(q) int jA##q, jB##q, jC##q; ulong2 rA##q, rB##q, rC##q;
  REP16(DECLV)
#undef DECLV

#define PRODA(q) jA##q = next_cand();
#define PRODB(q) jB##q = next_cand();
#define PRODC(q) jC##q = next_cand();
#define LOADA(q) rA##q = *(const ulong2*)&mrow[(size_t)(jA##q < 0 ? 0 : jA##q) * NT + 2 * l];
#define LOADB(q) rB##q = *(const ulong2*)&mrow[(size_t)(jB##q < 0 ? 0 : jB##q) * NT + 2 * l];
#define LOADC(q) rC##q = *(const ulong2*)&mrow[(size_t)(jC##q < 0 ? 0 : jC##q) * NT + 2 * l];
#define PROC(jv, rv) { int j = jv;                                            \
    u64 wj = getR(j < 0 ? 0 : (j >> 6));                                      \
    bool head = (j >= 0) && !((wj >> (j & 63)) & 1ull);                       \
    u64 hm = head ? ~0ull : 0ull;                                             \
    R0 |= rv.x & hm; R1 |= rv.y & hm;                                         \
    u64 bset = 1ull << (j & 63);                                              \
    bool own = ((j >> 7) == l);                                               \
    D0 |= (head && own && !((j >> 6) & 1)) ? bset : 0ull;                     \
    D1 |= (head && own && ((j >> 6) & 1)) ? bset : 0ull; }
#define PROCA(q) PROC(jA##q, rA##q)
#define PROCB(q) PROC(jB##q, rB##q)
#define PROCC(q) PROC(jC##q, rC##q)

  // prologue: fill 3 batches (48 candidates in flight)
  REP16(PRODA) REP16(LOADA)
  REP16(PRODB) REP16(LOADB)
  REP16(PRODC) REP16(LOADC)

  while (true) {
    if (jA0 < 0) break;      // stream exhausted (padding is all-tail)
    REP16(PROCA)
    REP16(PRODA)
    REP16(LOADA)
    if (jB0 < 0) break;
    REP16(PROCB)
    REP16(PRODB)
    REP16(LOADB)
    if (jC0 < 0) break;
    REP16(PROCC)
    REP16(PRODC)
    REP16(LOADC)
  }

  D[2 * l] = D0;
  D[2 * l + 1] = D1;
}

// ---------------------------------------------------------------------------
// K5: parallel cluster assignment + segment atomics. cluster[j] = first head
// adjacent to j (head index provably <= j) -> scan only tiles k <= gy.
// Fused "first index at cluster-max y2" via ONE packed u64 atomicMax:
// (y2_bits << 32) | ~j  -- y2 >= 0 so uint order == float order; tie -> min j.
// ---------------------------------------------------------------------------
__global__ __launch_bounds__(256) void k_cluster(const u64* __restrict__ mtile,
                                                 const u64* __restrict__ D,
                                                 const float* __restrict__ ss,
                                                 const float* __restrict__ by2s,
                                                 int* __restrict__ cluster,
                                                 int* __restrict__ cnt,
                                                 float* __restrict__ prob,
                                                 u64* __restrict__ pk) {
  __shared__ u64 hlds[NT];
  __shared__ int red[4][64];
  int gy = blockIdx.x;
  if (threadIdx.x < NT) hlds[threadIdx.x] = D[threadIdx.x];
  __syncthreads();
  int w = threadIdx.x >> 6, r = threadIdx.x & 63;
  int best = 0x7fffffff;
  for (int k = w; k <= gy; k += 4) {      // per-group candidates ascend with k
    u64 v = mtile[((size_t)gy * NT + k) * 64 + r] & hlds[k];
    if (v) { best = k * 64 + __builtin_ctzll(v); break; }
  }
  red[w][r] = best;
  __syncthreads();
  if (w == 0) {
    int b = min(min(red[0][r], red[1][r]), min(red[2][r], red[3][r]));
    int j = gy * 64 + r;
    cluster[j] = b;
    atomicAdd(&cnt[b], 1);
    atomicAdd(&prob[b], ss[j]);
    atomicMax((unsigned long long*)&pk[b],
              ((u64)__float_as_uint(by2s[j]) << 32) | (u64)(0xFFFFFFFFu - (unsigned)j));
  }
}

// ---------------------------------------------------------------------------
// K6: outputs. out[j][0..4] then keep[j] appended (floats 0/1).
// first index recovered from packed atomicMax: ~low32(pk).
// ---------------------------------------------------------------------------
__global__ __launch_bounds__(256) void k_out(const int* __restrict__ cluster,
                                             const float* __restrict__ bx1s, const float* __restrict__ by1s,
                                             const float* __restrict__ bx2s, const float* __restrict__ by2s,
                                             const int* __restrict__ cnt,
                                             const float* __restrict__ prob,
                                             const u64* __restrict__ pk,
                                             const int* __restrict__ num_models,
                                             float* __restrict__ out) {
  int j = blockIdx.x * 256 + threadIdx.x;
  if (j >= N) return;
  int c = cluster[j];
  int nm = num_models[0];
  bool valid = (float)cnt[c] >= (float)nm / 3.0f;
  unsigned fj = 0xFFFFFFFFu - (unsigned)(pk[c] & 0xFFFFFFFFull);
  bool keep = (fj == (unsigned)j) && valid;
  float o0 = 0.f, o1 = 0.f, o2 = 0.f, o3 = 0.f, o4 = 0.f;
  if (keep) {
    o0 = bx1s[j]; o1 = by1s[j]; o2 = bx2s[j]; o3 = by2s[j];
    o4 = prob[c] / (float)nm;
  }
  out[j * 5 + 0] = o0;
  out[j * 5 + 1] = o1;
  out[j * 5 + 2] = o2;
  out[j * 5 + 3] = o3;
  out[j * 5 + 4] = o4;
  out[N * 5 + j] = keep ? 1.0f : 0.0f;
}

// ---------------------------------------------------------------------------
extern "C" void kernel_launch(void* const* d_in, const int* in_sizes, int n_in,
                              void* d_out, int out_size, void* d_ws, size_t ws_size,
                              hipStream_t stream) {
  const float* boxes = (const float*)d_in[0];
  const float* scores = (const float*)d_in[1];
  const int* num_models = (const int*)d_in[2];
  float* out = (float*)d_out;

  char* p = (char*)d_ws;
  auto take = [&](size_t bytes) {
    char* r = p;
    p += (bytes + 255) & ~(size_t)255;
    return r;
  };
  int* rankpart = (int*)take((size_t)8 * N * 4);
  float* bx1s = (float*)take((size_t)N * 4);
  float* by1s = (float*)take((size_t)N * 4);
  float* bx2s = (float*)take((size_t)N * 4);
  float* by2s = (float*)take((size_t)N * 4);
  float* ss   = (float*)take((size_t)N * 4);
  float* areas= (float*)take((size_t)N * 4);
  int* cluster= (int*)take((size_t)N * 4);
  int* cnt    = (int*)take((size_t)N * 4);
  float* prob = (float*)take((size_t)N * 4);
  u64* pk     = (u64*)take((size_t)N * 8);            // packed (y2max, ~first)
  u64* D      = (u64*)take((size_t)NT * 8);           // head bitmap
  u64* mtile  = (u64*)take((size_t)NT * NT * 64 * 8); // 8 MiB tiled adjacency
  u64* mrow   = (u64*)take((size_t)N * NT * 8);       // 8 MiB row-major adjacency

  k_rank<<<dim3(N / 256, 8), 256, 0, stream>>>(scores, rankpart);
  k_scatter<<<N / 256, 256, 0, stream>>>(boxes, scores, rankpart,
                                         bx1s, by1s, bx2s, by2s, ss, areas,
                                         cnt, prob, pk);
  k_adj<<<NT * (NT + 1) / 2, 64, 0, stream>>>(bx1s, by1s, bx2s, by2s, areas, mtile, mrow);
  k_sweep<<<1, 64, 0, stream>>>(mrow, D);
  k_cluster<<<NT, 256, 0, stream>>>(mtile, D, ss, by2s, cluster, cnt, prob, pk);
  k_out<<<N / 256, 256, 0, stream>>>(cluster, bx1s, by1s, bx2s, by2s, cnt, prob, pk, num_models, out);
}

// Round 4
// 774.215 us; speedup vs baseline: 3.4516x; 1.2035x over previous
//
#include <hip/hip_runtime.h>
#include <cstdint>

#define N 8192
#define NT 128      // 64-col chunks per row (N/64)
typedef unsigned long long u64;
typedef unsigned int u32;
typedef u32 u32x4 __attribute__((ext_vector_type(4)));

// ---------------------------------------------------------------------------
// K1: rank by counting, keys recomputed inline from scores (descending score,
// stable ascending index). Partial counts per y-slab -> rankpart[8][N].
// ---------------------------------------------------------------------------
__global__ __launch_bounds__(256) void k_rank(const float* __restrict__ scores,
                                              int* __restrict__ rankpart) {
  __shared__ u64 tile[1024];
  int e = blockIdx.x * 256 + threadIdx.x;
  int j0 = blockIdx.y * 1024;
  for (int t = threadIdx.x; t < 1024; t += 256) {
    int j = j0 + t;
    tile[t] = ((u64)__float_as_uint(scores[j]) << 32) | (unsigned)(0xFFFFFFFFu - (unsigned)j);
  }
  __syncthreads();
  u64 ke = ((u64)__float_as_uint(scores[e]) << 32) | (unsigned)(0xFFFFFFFFu - (unsigned)e);
  int c = 0;
#pragma unroll 8
  for (int k = 0; k < 1024; ++k) c += (tile[k] > ke) ? 1 : 0;
  rankpart[blockIdx.y * N + e] = c;
}

// ---------------------------------------------------------------------------
// K2: sum rank partials + scatter into sorted SoA + init aux.
// ---------------------------------------------------------------------------
__global__ __launch_bounds__(256) void k_scatter(const float* __restrict__ boxes,
                                                 const float* __restrict__ scores,
                                                 const int* __restrict__ rankpart,
                                                 float* __restrict__ bx1s, float* __restrict__ by1s,
                                                 float* __restrict__ bx2s, float* __restrict__ by2s,
                                                 float* __restrict__ ss, float* __restrict__ areas,
                                                 int* __restrict__ cnt,
                                                 float* __restrict__ prob,
                                                 u64* __restrict__ pk) {
#pragma clang fp contract(off)
  int i = blockIdx.x * 256 + threadIdx.x;
  if (i >= N) return;
  int r = 0;
#pragma unroll
  for (int q = 0; q < 8; ++q) r += rankpart[q * N + i];
  float x1 = fminf(fmaxf(boxes[i * 4 + 0], 0.0f), 1920.0f);
  float y1 = fminf(fmaxf(boxes[i * 4 + 1], 0.0f), 1080.0f);
  float x2 = fminf(fmaxf(boxes[i * 4 + 2], 0.0f), 1920.0f);
  float y2 = fminf(fmaxf(boxes[i * 4 + 3], 0.0f), 1080.0f);
  bx1s[r] = x1; by1s[r] = y1; bx2s[r] = x2; by2s[r] = y2;
  ss[r] = scores[i];
  areas[r] = (x2 - x1 + 1.0f) * (y2 - y1 + 1.0f);
  cnt[i] = 0;
  prob[i] = 0.0f;
  pk[i] = 0ull;
}

// ---------------------------------------------------------------------------
// K3: adjacency, SYMMETRIC lower-triangle blocks + ballot transpose.
// Band trick (verified absmax 0.0): iou>0.5 <=> 2*inter>uni whenever
// |2*inter-uni| > 1e-6*uni; only in-band lanes take the exact IEEE divide.
// fp contract OFF everywhere; matrix float-exact symmetric.
// ---------------------------------------------------------------------------
__global__ __launch_bounds__(64) void k_adj(const float* __restrict__ bx1s, const float* __restrict__ by1s,
                                            const float* __restrict__ bx2s, const float* __restrict__ by2s,
                                            const float* __restrict__ areas,
                                            u64* __restrict__ mtile,
                                            u64* __restrict__ mrow) {
#pragma clang fp contract(off)
  __shared__ float jx1[64], jy1[64], jx2[64], jy2[64], ja[64];
  int p = blockIdx.x;
  int gy = (int)((sqrtf(8.0f * (float)p + 1.0f) - 1.0f) * 0.5f);
  while ((gy + 1) * (gy + 2) / 2 <= p) ++gy;
  while (gy * (gy + 1) / 2 > p) --gy;
  int gx = p - gy * (gy + 1) / 2;

  int l = threadIdx.x;
  int j = gx * 64 + l;
  jx1[l] = bx1s[j]; jy1[l] = by1s[j]; jx2[l] = bx2s[j]; jy2[l] = by2s[j]; ja[l] = areas[j];
  __syncthreads();
  int i = gy * 64 + l;
  float x1 = bx1s[i], y1 = by1s[i], x2 = bx2s[i], y2 = by2s[i], ai = areas[i];
  u64 bits = 0;
#pragma unroll 4
  for (int jj = 0; jj < 64; ++jj) {
    float ix1 = fmaxf(x1, jx1[jj]);
    float iy1 = fmaxf(y1, jy1[jj]);
    float ix2 = fminf(x2, jx2[jj]);
    float iy2 = fminf(y2, jy2[jj]);
    float iw = fmaxf(ix2 - ix1 + 1.0f, 0.0f);
    float ih = fmaxf(iy2 - iy1 + 1.0f, 0.0f);
    float inter = iw * ih;
    float uni = (ai + ja[jj]) - inter;   // uni > 0 always (areas >= 1)
    float t = inter + inter;             // exact (x2)
    bool gt = t > uni;
    bool amb = fabsf(t - uni) <= 1e-6f * uni;
    if (__ballot(amb) != 0ull) {         // ~never taken
      float iou = inter / uni;           // exact IEEE div, matches numpy
      if (amb) gt = iou > 0.5f;
    }
    bits |= ((u64)gt) << jj;
  }
  mtile[((size_t)gy * NT + gx) * 64 + l] = bits;
  mrow[(size_t)i * NT + gx] = bits;
  if (gx != gy) {
    u64 tb = 0;
#pragma unroll 8
    for (int c = 0; c < 64; ++c) {
      u64 wb = __ballot((bits >> c) & 1ull);
      tb = (l == c) ? wb : tb;
    }
    mtile[((size_t)gx * NT + gy) * 64 + l] = tb;
    mrow[(size_t)(gx * 64 + l) * NT + gy] = tb;
  }
}

// ---------------------------------------------------------------------------
// K4: EXACT single-sweep greedy classification, ONE wave, dual (suppressed-
// bitmap) form. Algorithm identical to rounds 2/3 (absmax 0.0 both).
//
// Round-3 failure: plain C loads let the scheduler SINK each load next to its
// use (pressure-minimizing), collapsing the pipeline to one memory latency
// per candidate (815us = 2700 x ~725cy). Fix: pin the schedule (T4 style):
//  * loads are asm volatile global_load_dwordx4 into NAMED 128-bit regs --
//    cannot be sunk/rematerialized/reordered; compiler inserts NO waits for
//    them (it doesn't know they're VMEM) -> no conservative vmcnt(0) drains.
//  * 4 rotating groups x 8 candidates; constant s_waitcnt vmcnt(24) before
//    each group's PROC (3 newer groups = 24 loads stay in flight; never 0).
//  * sched_barrier(0) immediately after each waitcnt (rule #18: register-only
//    consumers otherwise get hoisted past inline-asm waits).
//  * exactly 8 loads issued per group ALWAYS (exhausted slots load row 0) so
//    the vmcnt arithmetic stays constant.
//
// Inner loop slimmed: no D-bitmap updates. Head rows are ORed with the SELF
// BIT MASKED, so at completion R = exact suppressed set and heads = ~R
// (heads are pairwise non-adjacent: no head row sets another head's bit).
//
// Invariant (greedy MIS): R = OR of rows of heads processed so far; bit j of
// R clear at j's turn <=> j is a head. Candidates = bits unsuppressed at scan
// time (sound superset, monotone scan -> no duplicates, ascending order).
// ---------------------------------------------------------------------------
#define REP8(M) M(0) M(1) M(2) M(3) M(4) M(5) M(6) M(7)

__global__ __launch_bounds__(64, 1) void k_sweep(const u64* __restrict__ mrow,
                                                 u64* __restrict__ D) {
  int l = threadIdx.x;
  u64 R0 = 0, R1 = 0;      // lane l holds suppressed-words 2l, 2l+1
  int sw = 0, swb = 0;     // scan word pointer / current word index
  u64 sm = 0;              // remaining candidate bits in word swb

  auto getR64 = [&](int w) -> u64 {                  // w uniform
    u64 x = (w & 1) ? R1 : R0;
    u32 lo = __builtin_amdgcn_readlane((u32)x, (w >> 1) & 63);
    u32 hi = __builtin_amdgcn_readlane((u32)(x >> 32), (w >> 1) & 63);
    return ((u64)hi << 32) | (u64)lo;
  };
  auto next_cand = [&]() -> int {                    // uniform result
    while (sm == 0) {
      if (sw >= NT) return -1;
      swb = sw;
      sm = ~getR64(sw);    // unsuppressed-at-scan-time = candidate superset
      ++sw;
    }
    int b = __builtin_ctzll(sm);
    sm &= sm - 1;
    return swb * 64 + b;
  };

#define DECLV(q) int jA##q, jB##q, jC##q, jD##q; u32x4 rA##q, rB##q, rC##q, rD##q;
  REP8(DECLV)
#undef DECLV

#define PRODX(G, q) j##G##q = next_cand();
#define ISSUEX(G, q) {                                                        \
    int jj_ = (j##G##q < 0) ? 0 : j##G##q;                                    \
    const void* ap_ = (const char*)mrow + ((size_t)jj_ << 10) + (l << 4);     \
    asm volatile("global_load_dwordx4 %0, %1, off"                            \
                 : "=v"(r##G##q) : "v"(ap_) : "memory");                      \
  }
#define PROCX(G, q) {                                                         \
    int j_ = j##G##q;                                                         \
    u32x4 rv_ = r##G##q;                                                      \
    int jw_ = j_ >> 6;                                                        \
    u64 t_ = (jw_ & 1) ? R1 : R0;                                             \
    u32 half_ = ((j_ >> 5) & 1) ? (u32)(t_ >> 32) : (u32)t_;                  \
    u32 word_ = __builtin_amdgcn_readlane(half_, (j_ >> 7) & 63);             \
    bool head_ = (j_ >= 0) && !((word_ >> (j_ & 31)) & 1u);                   \
    u64 hm_ = head_ ? ~0ull : 0ull;                                           \
    u64 sb_ = ~(1ull << (j_ & 63));                                           \
    u64 m0_ = hm_ & ((jw_ == 2 * l) ? sb_ : ~0ull);                           \
    u64 m1_ = hm_ & ((jw_ == 2 * l + 1) ? sb_ : ~0ull);                       \
    u64 lo_ = ((u64)rv_.y << 32) | (u64)rv_.x;                                \
    u64 hi_ = ((u64)rv_.w << 32) | (u64)rv_.z;                                \
    R0 |= lo_ & m0_;                                                          \
    R1 |= hi_ & m1_;                                                          \
  }
#define PRODA(q) PRODX(A, q)
#define PRODB(q) PRODX(B, q)
#define PRODC(q) PRODX(C, q)
#define PRODD(q) PRODX(D, q)
#define ISSUEA(q) ISSUEX(A, q)
#define ISSUEB(q) ISSUEX(B, q)
#define ISSUEC(q) ISSUEX(C, q)
#define ISSUED(q) ISSUEX(D, q)
#define PROCA(q) PROCX(A, q)
#define PROCB(q) PROCX(B, q)
#define PROCC(q) PROCX(C, q)
#define PROCD(q) PROCX(D, q)

#define WAIT24 { asm volatile("s_waitcnt vmcnt(24)" ::: "memory");            \
                 __builtin_amdgcn_sched_barrier(0); }

  // prologue: fill 4 groups (32 loads in flight)
  REP8(PRODA) REP8(ISSUEA)
  REP8(PRODB) REP8(ISSUEB)
  REP8(PRODC) REP8(ISSUEC)
  REP8(PRODD) REP8(ISSUED)

  while (true) {
    if (jA0 < 0) break;      // production monotone -> all groups exhausted
    WAIT24                   // oldest 8 (A) complete; 24 newer stay in flight
    REP8(PROCA)
    REP8(PRODA) REP8(ISSUEA)
    if (jB0 < 0) break;
    WAIT24
    REP8(PROCB)
    REP8(PRODB) REP8(ISSUEB)
    if (jC0 < 0) break;
    WAIT24
    REP8(PROCC)
    REP8(PRODC) REP8(ISSUEC)
    if (jD0 < 0) break;
    WAIT24
    REP8(PROCD)
    REP8(PRODD) REP8(ISSUED)
  }

  asm volatile("s_waitcnt vmcnt(0)" ::: "memory");   // drain before endpgm
  __builtin_amdgcn_sched_barrier(0);
  D[2 * l] = ~R0;            // heads = complement of exact suppressed set
  D[2 * l + 1] = ~R1;
}

// ---------------------------------------------------------------------------
// K5: parallel cluster assignment + segment atomics. cluster[j] = first head
// adjacent to j (head index provably <= j) -> scan only tiles k <= gy.
// Fused "first index at cluster-max y2" via ONE packed u64 atomicMax:
// (y2_bits << 32) | ~j  -- y2 >= 0 so uint order == float order; tie -> min j.
// ---------------------------------------------------------------------------
__global__ __launch_bounds__(256) void k_cluster(const u64* __restrict__ mtile,
                                                 const u64* __restrict__ D,
                                                 const float* __restrict__ ss,
                                                 const float* __restrict__ by2s,
                                                 int* __restrict__ cluster,
                                                 int* __restrict__ cnt,
                                                 float* __restrict__ prob,
                                                 u64* __restrict__ pk) {
  __shared__ u64 hlds[NT];
  __shared__ int red[4][64];
  int gy = blockIdx.x;
  if (threadIdx.x < NT) hlds[threadIdx.x] = D[threadIdx.x];
  __syncthreads();
  int w = threadIdx.x >> 6, r = threadIdx.x & 63;
  int best = 0x7fffffff;
  for (int k = w; k <= gy; k += 4) {      // per-group candidates ascend with k
    u64 v = mtile[((size_t)gy * NT + k) * 64 + r] & hlds[k];
    if (v) { best = k * 64 + __builtin_ctzll(v); break; }
  }
  red[w][r] = best;
  __syncthreads();
  if (w == 0) {
    int b = min(min(red[0][r], red[1][r]), min(red[2][r], red[3][r]));
    int j = gy * 64 + r;
    cluster[j] = b;
    atomicAdd(&cnt[b], 1);
    atomicAdd(&prob[b], ss[j]);
    atomicMax((unsigned long long*)&pk[b],
              ((u64)__float_as_uint(by2s[j]) << 32) | (u64)(0xFFFFFFFFu - (unsigned)j));
  }
}

// ---------------------------------------------------------------------------
// K6: outputs. out[j][0..4] then keep[j] appended (floats 0/1).
// first index recovered from packed atomicMax: ~low32(pk).
// ---------------------------------------------------------------------------
__global__ __launch_bounds__(256) void k_out(const int* __restrict__ cluster,
                                             const float* __restrict__ bx1s, const float* __restrict__ by1s,
                                             const float* __restrict__ bx2s, const float* __restrict__ by2s,
                                             const int* __restrict__ cnt,
                                             const float* __restrict__ prob,
                                             const u64* __restrict__ pk,
                                             const int* __restrict__ num_models,
                                             float* __restrict__ out) {
  int j = blockIdx.x * 256 + threadIdx.x;
  if (j >= N) return;
  int c = cluster[j];
  int nm = num_models[0];
  bool valid = (float)cnt[c] >= (float)nm / 3.0f;
  unsigned fj = 0xFFFFFFFFu - (unsigned)(pk[c] & 0xFFFFFFFFull);
  bool keep = (fj == (unsigned)j) && valid;
  float o0 = 0.f, o1 = 0.f, o2 = 0.f, o3 = 0.f, o4 = 0.f;
  if (keep) {
    o0 = bx1s[j]; o1 = by1s[j]; o2 = bx2s[j]; o3 = by2s[j];
    o4 = prob[c] / (float)nm;
  }
  out[j * 5 + 0] = o0;
  out[j * 5 + 1] = o1;
  out[j * 5 + 2] = o2;
  out[j * 5 + 3] = o3;
  out[j * 5 + 4] = o4;
  out[N * 5 + j] = keep ? 1.0f : 0.0f;
}

// ---------------------------------------------------------------------------
extern "C" void kernel_launch(void* const* d_in, const int* in_sizes, int n_in,
                              void* d_out, int out_size, void* d_ws, size_t ws_size,
                              hipStream_t stream) {
  const float* boxes = (const float*)d_in[0];
  const float* scores = (const float*)d_in[1];
  const int* num_models = (const int*)d_in[2];
  float* out = (float*)d_out;

  char* p = (char*)d_ws;
  auto take = [&](size_t bytes) {
    char* r = p;
    p += (bytes + 255) & ~(size_t)255;
    return r;
  };
  int* rankpart = (int*)take((size_t)8 * N * 4);
  float* bx1s = (float*)take((size_t)N * 4);
  float* by1s = (float*)take((size_t)N * 4);
  float* bx2s = (float*)take((size_t)N * 4);
  float* by2s = (float*)take((size_t)N * 4);
  float* ss   = (float*)take((size_t)N * 4);
  float* areas= (float*)take((size_t)N * 4);
  int* cluster= (int*)take((size_t)N * 4);
  int* cnt    = (int*)take((size_t)N * 4);
  float* prob = (float*)take((size_t)N * 4);
  u64* pk     = (u64*)take((size_t)N * 8);            // packed (y2max, ~first)
  u64* D      = (u64*)take((size_t)NT * 8);           // head bitmap
  u64* mtile  = (u64*)take((size_t)NT * NT * 64 * 8); // 8 MiB tiled adjacency
  u64* mrow   = (u64*)take((size_t)N * NT * 8);       // 8 MiB row-major adjacency

  k_rank<<<dim3(N / 256, 8), 256, 0, stream>>>(scores, rankpart);
  k_scatter<<<N / 256, 256, 0, stream>>>(boxes, scores, rankpart,
                                         bx1s, by1s, bx2s, by2s, ss, areas,
                                         cnt, prob, pk);
  k_adj<<<NT * (NT + 1) / 2, 64, 0, stream>>>(bx1s, by1s, bx2s, by2s, areas, mtile, mrow);
  k_sweep<<<1, 64, 0, stream>>>(mrow, D);
  k_cluster<<<NT, 256, 0, stream>>>(mtile, D, ss, by2s, cluster, cnt, prob, pk);
  k_out<<<N / 256, 256, 0, stream>>>(cluster, bx1s, by1s, bx2s, by2s, cnt, prob, pk, num_models, out);
}